// Round 2
// baseline (1248.071 us; speedup 1.0000x reference)
//
#include <hip/hip_runtime.h>
#include <math.h>

#define B    64
#define D    3072
#define L    64
#define N    8000
#define NC   10
#define NT   64          // n per block
#define DC   64          // d chunk
#define NBLK (N / NT)    // 125
#define NCHUNK (D / DC)  // 48

#define LOGITS_OFF 0
#define RECS_OFF   640
#define MUS_OFF    (640 + NC * B * D)          // 1,966,720
#define LV_OFF     (MUS_OFF + NC * B * L)      // 2,007,680

// ---------------- prep: transpose X, kld, x_sq ----------------
__global__ void prep_kernel(const float* __restrict__ xf, const float* __restrict__ zf,
                            float* __restrict__ xt, float* __restrict__ kld,
                            float* __restrict__ xsq) {
    int blk = blockIdx.x, t = threadIdx.x;
    if (blk < 768) {                      // X transpose: [B][D] -> [D][B]
        int id = blk * 256 + t;           // < 196608
        int b = id / D, d = id % D;
        xt[d * B + b] = xf[id];
    } else if (blk < 800) {               // kld[n] = 0.5 * ||z_n||^2
        int n = (blk - 768) * 256 + t;
        if (n < N) {
            const float4* zp = (const float4*)(zf + (size_t)n * L);
            float s = 0.f;
            #pragma unroll
            for (int k = 0; k < 16; ++k) {
                float4 v = zp[k];
                s += v.x * v.x + v.y * v.y + v.z * v.z + v.w * v.w;
            }
            kld[n] = 0.5f * s;
        }
    } else {                              // x_sq[b]
        if (t < 64) {
            float s = 0.f;
            for (int d = 0; d < D; ++d) { float v = xf[t * D + d]; s += v * v; }
            xsq[t] = s;
        }
    }
}

// ---------------- main: fused decoder + cross + min/argmin ----------------
__global__ __launch_bounds__(256, 2)
void loss_kernel(const float* __restrict__ xt, const float* __restrict__ zf,
                 const float* __restrict__ dw, const float* __restrict__ db,
                 const float* __restrict__ kld, const float* __restrict__ xsq,
                 float* __restrict__ pmin, int* __restrict__ pidx) {
    const int c  = blockIdx.x / NBLK;
    const int nb = blockIdx.x % NBLK;
    const int t  = threadIdx.x;

    __shared__ float Zs[L][68];   // [l][n]
    __shared__ float Ws[DC][68];  // [l][d]  (row=l, col=d-local)
    __shared__ float Xs[DC][68];  // [d][b]
    __shared__ float Rs[DC][68];  // [d][n]
    __shared__ float kld_s[64], xsq_s[64], rsq_s[64], Bs[64];

    // load Z tile transposed: Zs[l][n]
    for (int k = t; k < NT * L; k += 256) {
        int n = k >> 6, l = k & 63;
        Zs[l][n] = zf[(size_t)(nb * NT + n) * L + l];
    }
    if (t < 64) kld_s[t] = kld[nb * NT + t];
    else if (t < 128) xsq_s[t - 64] = xsq[t - 64];

    const int tn1 = t >> 4, td1 = t & 15;    // phase-1 map: 4n x 4d
    const int n0a = tn1 * 4, d0a = td1 * 4;
    const int tb2 = t >> 4, tn2 = t & 15;    // phase-2 map: 4b x 4n
    const int b0 = tb2 * 4, n0b = tn2 * 4;

    float rsq_p[4] = {0.f, 0.f, 0.f, 0.f};
    double acc2d[4][4] = {{0.0}};   // cross accumulated in double across chunks

    const float* wc = dw + (size_t)c * L * D;
    const float* bc = db + (size_t)c * D;

    for (int ch = 0; ch < NCHUNK; ++ch) {
        __syncthreads();   // previous chunk fully consumed
        // stage W chunk [L][DC] and X^T chunk [DC][B]
        for (int k = t; k < (L * DC) / 4; k += 256) {
            int row = k >> 4, col = (k & 15) << 2;
            *(float4*)&Ws[row][col] =
                *(const float4*)&wc[(size_t)row * D + ch * DC + col];
        }
        for (int k = t; k < (DC * B) / 4; k += 256) {
            int row = k >> 4, col = (k & 15) << 2;
            *(float4*)&Xs[row][col] =
                *(const float4*)&xt[(size_t)(ch * DC + row) * B + col];
        }
        if (t < 16) *(float4*)&Bs[t * 4] = *(const float4*)&bc[ch * DC + t * 4];
        __syncthreads();

        // phase 1: R[n][d] = sigmoid(Z.W + b), accumulate r^2
        float acc[4][4] = {{0.f}};
        #pragma unroll 8
        for (int l = 0; l < L; ++l) {
            float4 zv = *(const float4*)&Zs[l][n0a];
            float4 wv = *(const float4*)&Ws[l][d0a];
            float zz[4] = {zv.x, zv.y, zv.z, zv.w};
            float ww[4] = {wv.x, wv.y, wv.z, wv.w};
            #pragma unroll
            for (int i = 0; i < 4; ++i)
                #pragma unroll
                for (int j = 0; j < 4; ++j)
                    acc[i][j] = __builtin_fmaf(zz[i], ww[j], acc[i][j]);
        }
        #pragma unroll
        for (int j = 0; j < 4; ++j) {
            float bv = Bs[d0a + j];
            float rr[4];
            #pragma unroll
            for (int i = 0; i < 4; ++i) {
                float r = 1.0f / (1.0f + __expf(-(acc[i][j] + bv)));
                rr[i] = r;
                rsq_p[i] = __builtin_fmaf(r, r, rsq_p[i]);
            }
            *(float4*)&Rs[d0a + j][n0a] = make_float4(rr[0], rr[1], rr[2], rr[3]);
        }
        __syncthreads();

        // phase 2: cross[b][n] += X[b][d] * R[n][d]  (fp32 within chunk)
        float acc2[4][4] = {{0.f}};
        #pragma unroll 8
        for (int d = 0; d < DC; ++d) {
            float4 xv = *(const float4*)&Xs[d][b0];
            float4 rv = *(const float4*)&Rs[d][n0b];
            float xx[4] = {xv.x, xv.y, xv.z, xv.w};
            float rr[4] = {rv.x, rv.y, rv.z, rv.w};
            #pragma unroll
            for (int i = 0; i < 4; ++i)
                #pragma unroll
                for (int j = 0; j < 4; ++j)
                    acc2[i][j] = __builtin_fmaf(xx[i], rr[j], acc2[i][j]);
        }
        // drain chunk sums into double accumulators
        #pragma unroll
        for (int i = 0; i < 4; ++i)
            #pragma unroll
            for (int j = 0; j < 4; ++j)
                acc2d[i][j] += (double)acc2[i][j];
    }

    // reduce r^2 across the 16 lanes sharing the same n-group
    #pragma unroll
    for (int i = 0; i < 4; ++i) {
        float v = rsq_p[i];
        for (int m = 1; m < 16; m <<= 1) v += __shfl_xor(v, m, 16);
        if (td1 == 0) rsq_s[n0a + i] = v;
    }
    __syncthreads();

    // loss + argmin (double compare, first-occurrence tie-break)
    double bestv[4]; int besti[4];
    #pragma unroll
    for (int i = 0; i < 4; ++i) { bestv[i] = 1.0e300; besti[i] = 0x7fffffff; }
    #pragma unroll
    for (int j = 0; j < 4; ++j) {
        int nglob = nb * NT + n0b + j;
        double cj = (double)rsq_s[n0b + j] + (double)kld_s[n0b + j];
        #pragma unroll
        for (int i = 0; i < 4; ++i) {
            double v = (double)xsq_s[b0 + i] + cj - 2.0 * acc2d[i][j];
            if (v < bestv[i] || (v == bestv[i] && nglob < besti[i])) {
                bestv[i] = v; besti[i] = nglob;
            }
        }
    }
    for (int m = 1; m < 16; m <<= 1) {
        #pragma unroll
        for (int i = 0; i < 4; ++i) {
            double ov = __shfl_xor(bestv[i], m, 16);
            int    oi = __shfl_xor(besti[i], m, 16);
            if (ov < bestv[i] || (ov == bestv[i] && oi < besti[i])) {
                bestv[i] = ov; besti[i] = oi;
            }
        }
    }
    if (tn2 == 0) {
        #pragma unroll
        for (int i = 0; i < 4; ++i) {
            pmin[((size_t)c * NBLK + nb) * B + b0 + i] = (float)bestv[i];
            pidx[((size_t)c * NBLK + nb) * B + b0 + i] = besti[i];
        }
    }
}

// ---------------- reduce partial mins -> logits + final idx ----------------
__global__ void reduce_kernel(const float* __restrict__ pmin, const int* __restrict__ pidx,
                              float* __restrict__ out, int* __restrict__ fidx) {
    int c = blockIdx.x, b = threadIdx.x;   // 10 blocks x 64 threads
    float bv = 3.4e38f; int bi = 0x7fffffff;
    for (int nb = 0; nb < NBLK; ++nb) {
        float v = pmin[((size_t)c * NBLK + nb) * B + b];
        int   i = pidx[((size_t)c * NBLK + nb) * B + b];
        if (v < bv || (v == bv && i < bi)) { bv = v; bi = i; }
    }
    out[LOGITS_OFF + b * NC + c] = -bv;
    fidx[c * B + b] = bi;
}

// ---------------- final: selected reconstruction + mus + logvars ----------------
__global__ __launch_bounds__(256)
void final_kernel(const float* __restrict__ zf, const float* __restrict__ dw,
                  const float* __restrict__ db, const int* __restrict__ fidx,
                  float* __restrict__ out) {
    int c = blockIdx.x >> 6;
    int b = blockIdx.x & 63;
    int t = threadIdx.x;
    int n = fidx[c * B + b];
    __shared__ float zsh[64];
    if (t < 64) zsh[t] = zf[(size_t)n * L + t];
    __syncthreads();
    const float* wcc = dw + (size_t)c * L * D;
    float* rout = out + RECS_OFF + (size_t)(c * B + b) * D;
    for (int d = t; d < D; d += 256) {
        float a = db[(size_t)c * D + d];
        #pragma unroll 8
        for (int l = 0; l < L; ++l)
            a = __builtin_fmaf(zsh[l], wcc[(size_t)l * D + d], a);
        rout[d] = 1.0f / (1.0f + __expf(-a));
    }
    if (t < 64) {
        out[MUS_OFF + (size_t)(c * B + b) * L + t] = zsh[t];
        out[LV_OFF  + (size_t)(c * B + b) * L + t] = 0.0f;
    }
}

extern "C" void kernel_launch(void* const* d_in, const int* in_sizes, int n_in,
                              void* d_out, int out_size, void* d_ws, size_t ws_size,
                              hipStream_t stream) {
    const float* xf = (const float*)d_in[0];
    const float* zf = (const float*)d_in[1];
    const float* dw = (const float*)d_in[2];
    const float* db = (const float*)d_in[3];
    float* out = (float*)d_out;
    char* ws = (char*)d_ws;

    float* xt   = (float*)(ws);                  // 196608 floats
    float* kld  = (float*)(ws + 786432);         // 8000 floats
    float* xsq  = (float*)(ws + 818432);         // 64 floats
    float* pmin = (float*)(ws + 818688);         // 80000 floats
    int*   pidx = (int*)  (ws + 1138688);        // 80000 ints
    int*   fidx = (int*)  (ws + 1458688);        // 640 ints

    hipLaunchKernelGGL(prep_kernel, dim3(801), dim3(256), 0, stream, xf, zf, xt, kld, xsq);
    hipLaunchKernelGGL(loss_kernel, dim3(NC * NBLK), dim3(256), 0, stream,
                       xt, zf, dw, db, kld, xsq, pmin, pidx);
    hipLaunchKernelGGL(reduce_kernel, dim3(NC), dim3(64), 0, stream, pmin, pidx, out, fidx);
    hipLaunchKernelGGL(final_kernel, dim3(NC * B), dim3(256), 0, stream, zf, dw, db, fidx, out);
}

// Round 5
// 608.818 us; speedup vs baseline: 2.0500x; 2.0500x over previous
//
#include <hip/hip_runtime.h>
#include <math.h>

#define B    64
#define D    3072
#define L    64
#define N    8000
#define NC   10
#define NT   64          // n per block
#define DC   32          // d per chunk
#define NBLK (N / NT)    // 125
#define NCH  (D / DC)    // 96

#define LOGITS_OFF 0
#define RECS_OFF   640
#define MUS_OFF    (640 + NC * B * D)          // 1,966,720
#define LV_OFF     (MUS_OFF + NC * B * L)      // 2,007,680

typedef __attribute__((ext_vector_type(8)))  short bf16x8;
typedef __attribute__((ext_vector_type(16))) float f32x16;

// pack truncated-bf16(lo) | truncated-bf16(hi)<<16
__device__ __forceinline__ unsigned pk_hi2(float lo, float hi) {
    return __builtin_amdgcn_perm(__float_as_uint(hi), __float_as_uint(lo), 0x07060302u);
}
__device__ __forceinline__ float trunc_bf(float v) {
    return __uint_as_float(__float_as_uint(v) & 0xffff0000u);
}

// ---------------- prep: kld, x_sq ----------------
__global__ void prep_kernel(const float* __restrict__ xf, const float* __restrict__ zf,
                            float* __restrict__ kld, float* __restrict__ xsq) {
    int blk = blockIdx.x, t = threadIdx.x;
    if (blk < 32) {                       // kld[n] = 0.5*||z_n||^2
        int n = blk * 256 + t;
        if (n < N) {
            const float4* zp = (const float4*)(zf + (size_t)n * L);
            float s = 0.f;
            #pragma unroll
            for (int k = 0; k < 16; ++k) {
                float4 v = zp[k];
                s += v.x * v.x + v.y * v.y + v.z * v.z + v.w * v.w;
            }
            kld[n] = 0.5f * s;
        }
    } else {                              // xsq[b], blocks 32..95
        int b = blk - 32;
        float s = 0.f;
        #pragma unroll
        for (int k = 0; k < 12; ++k) {
            float v = xf[(size_t)b * D + k * 256 + t];
            s = __builtin_fmaf(v, v, s);
        }
        for (int m = 1; m < 64; m <<= 1) s += __shfl_xor(s, m);
        __shared__ float ps[4];
        if ((t & 63) == 0) ps[t >> 6] = s;
        __syncthreads();
        if (t == 0) xsq[b] = ps[0] + ps[1] + ps[2] + ps[3];
    }
}

// ---------------- main: split-bf16 MFMA fused loss ----------------
__global__ __launch_bounds__(128, 2)
void loss_kernel(const float* __restrict__ xf, const float* __restrict__ zf,
                 const float* __restrict__ dw, const float* __restrict__ db,
                 const float* __restrict__ kld, const float* __restrict__ xsq,
                 float* __restrict__ pmin, int* __restrict__ pidx) {
    const int tid  = threadIdx.x;
    const int nh   = tid >> 6;      // wave id = n-half
    const int lane = tid & 63;
    const int lrow = lane & 31;
    const int h    = lane >> 5;

    const int c  = blockIdx.x / NBLK;
    const int nb = blockIdx.x % NBLK;
    const int n0 = nb * NT;

    __shared__ unsigned short Wls[2][DC][68];   // [plane][d][l] rows 136B (2-way banks)
    __shared__ unsigned short Xls[3][B][36];    // [plane][b][d] rows 72B
    __shared__ float  bias_s[DC];
    __shared__ float  xsq_s[B];
    __shared__ double vmin_s[2][B];
    __shared__ int    imin_s[2][B];

    const float* wc = dw + (size_t)c * L * D;
    const float* bc = db + (size_t)c * D;

    // ---- preload Z fragments (exact 2-way split), 4 ksteps x 2 planes ----
    bf16x8 zfrag[4][2];
    {
        const int n_g = n0 + 32 * nh + lrow;
        const float* zr = zf + (size_t)n_g * L;
        #pragma unroll
        for (int ks = 0; ks < 4; ++ks) {
            float4 a = *(const float4*)(zr + ks * 16 + h * 8);
            float4 bq = *(const float4*)(zr + ks * 16 + h * 8 + 4);
            float t0 = trunc_bf(a.x), t1 = trunc_bf(a.y), t2 = trunc_bf(a.z), t3 = trunc_bf(a.w);
            float t4 = trunc_bf(bq.x), t5 = trunc_bf(bq.y), t6 = trunc_bf(bq.z), t7 = trunc_bf(bq.w);
            union { unsigned u[4]; bf16x8 v; } p1, p2;
            p1.u[0] = pk_hi2(t0, t1); p1.u[1] = pk_hi2(t2, t3);
            p1.u[2] = pk_hi2(t4, t5); p1.u[3] = pk_hi2(t6, t7);
            p2.u[0] = pk_hi2(a.x - t0, a.y - t1); p2.u[1] = pk_hi2(a.z - t2, a.w - t3);
            p2.u[2] = pk_hi2(bq.x - t4, bq.y - t5); p2.u[3] = pk_hi2(bq.z - t6, bq.w - t7);
            zfrag[ks][0] = p1.v; zfrag[ks][1] = p2.v;
        }
    }
    if (tid < B) xsq_s[tid] = xsq[tid];

    // ---- staging prefetch regs; issue chunk 0 ----
    const int l0 = tid >> 3;            // 0..15
    const int d4 = 4 * (tid & 7);       // 0..28
    float4 gw[4], gx[4];
    float gbias = 0.f;
    #pragma unroll
    for (int p = 0; p < 4; ++p) {
        gw[p] = *(const float4*)(wc + (size_t)(16 * p + l0) * D + d4);
        gx[p] = *(const float4*)(xf + (size_t)(16 * p + l0) * D + d4);
    }
    if (tid < DC) gbias = bc[tid];

    f32x16 acc2a = (f32x16)0.0f, acc2b = (f32x16)0.0f;
    f32x16 sh2a  = (f32x16)0.0f, sh2b  = (f32x16)0.0f;
    double racc_d = 0.0;

    for (int ch = 0; ch < NCH; ++ch) {
        __syncthreads();                 // prev chunk LDS reads done
        // ---- write stage: split W (transposed scatter) + X (row pairs) ----
        #pragma unroll
        for (int p = 0; p < 4; ++p) {
            const int row = 16 * p + l0;
            float wv[4] = {gw[p].x, gw[p].y, gw[p].z, gw[p].w};
            #pragma unroll
            for (int i = 0; i < 4; ++i) {
                unsigned u = __float_as_uint(wv[i]);
                float t = __uint_as_float(u & 0xffff0000u);
                float r = wv[i] - t;
                Wls[0][d4 + i][row] = (unsigned short)(u >> 16);
                Wls[1][d4 + i][row] = (unsigned short)(__float_as_uint(r) >> 16);
            }
            float xv[4] = {gx[p].x, gx[p].y, gx[p].z, gx[p].w};
            float x1[4], xr[4], x2[4], x3[4];
            #pragma unroll
            for (int i = 0; i < 4; ++i) {
                x1[i] = trunc_bf(xv[i]); xr[i] = xv[i] - x1[i];
                x2[i] = trunc_bf(xr[i]); x3[i] = xr[i] - x2[i];
            }
            *(uint2*)&Xls[0][row][d4] = make_uint2(pk_hi2(x1[0], x1[1]), pk_hi2(x1[2], x1[3]));
            *(uint2*)&Xls[1][row][d4] = make_uint2(pk_hi2(x2[0], x2[1]), pk_hi2(x2[2], x2[3]));
            *(uint2*)&Xls[2][row][d4] = make_uint2(pk_hi2(x3[0], x3[1]), pk_hi2(x3[2], x3[3]));
        }
        if (tid < DC) bias_s[tid] = gbias;
        __syncthreads();                 // stage visible

        // ---- issue next-chunk global loads (latency hides under compute) ----
        {
            const int chn = (ch + 1 < NCH) ? ch + 1 : 0;
            #pragma unroll
            for (int p = 0; p < 4; ++p) {
                gw[p] = *(const float4*)(wc + (size_t)(16 * p + l0) * D + (size_t)chn * DC + d4);
                gx[p] = *(const float4*)(xf + (size_t)(16 * p + l0) * D + (size_t)chn * DC + d4);
            }
            if (tid < DC) gbias = bc[(size_t)chn * DC + tid];
        }

        // ---- GEMM1: Rt[d][n] = W^T · Z^T  (bf16x3), K=64 ----
        f32x16 rt = (f32x16)0.0f;
        #pragma unroll
        for (int ks = 0; ks < 4; ++ks) {
            const unsigned short* wr0 = &Wls[0][lrow][16 * ks + 8 * h];
            const unsigned short* wr1 = &Wls[1][lrow][16 * ks + 8 * h];
            uint2 a0 = *(const uint2*)wr0;       uint2 a1 = *(const uint2*)(wr0 + 4);
            uint2 b0 = *(const uint2*)wr1;       uint2 b1 = *(const uint2*)(wr1 + 4);
            union { unsigned u[4]; bf16x8 v; } w1, w2;
            w1.u[0] = a0.x; w1.u[1] = a0.y; w1.u[2] = a1.x; w1.u[3] = a1.y;
            w2.u[0] = b0.x; w2.u[1] = b0.y; w2.u[2] = b1.x; w2.u[3] = b1.y;
            rt = __builtin_amdgcn_mfma_f32_32x32x16_bf16(w1.v, zfrag[ks][0], rt, 0, 0, 0);
            rt = __builtin_amdgcn_mfma_f32_32x32x16_bf16(w1.v, zfrag[ks][1], rt, 0, 0, 0);
            rt = __builtin_amdgcn_mfma_f32_32x32x16_bf16(w2.v, zfrag[ks][0], rt, 0, 0, 0);
        }

        // ---- sigmoid + bias + r^2 ----
        float s[16];
        float ch_r2 = 0.f;
        #pragma unroll
        for (int reg = 0; reg < 16; ++reg) {
            int dl = (reg & 3) + 8 * (reg >> 2) + 4 * h;
            float a = rt[reg] + bias_s[dl];
            float r = 1.0f / (1.0f + __expf(-a));
            s[reg] = r;
            ch_r2 = __builtin_fmaf(r, r, ch_r2);
        }
        racc_d += (double)ch_r2;

        // ---- build GEMM2 B-fragments in-register (exact 3-way split + permlane swap) ----
        bf16x8 rfrag[2][3];
        #pragma unroll
        for (int ks2 = 0; ks2 < 2; ++ks2) {
            float t1[8], r1[8], t2[8], t3[8];
            #pragma unroll
            for (int e = 0; e < 8; ++e) {
                float v = s[8 * ks2 + e];
                t1[e] = trunc_bf(v);     r1[e] = v - t1[e];
                t2[e] = trunc_bf(r1[e]); t3[e] = r1[e] - t2[e];
            }
            #pragma unroll
            for (int pl = 0; pl < 3; ++pl) {
                const float* sp = (pl == 0) ? t1 : (pl == 1) ? t2 : t3;
                unsigned A0 = pk_hi2(sp[0], sp[1]);
                unsigned A1 = pk_hi2(sp[2], sp[3]);
                unsigned B0 = pk_hi2(sp[4], sp[5]);
                unsigned B1 = pk_hi2(sp[6], sp[7]);
                auto r02 = __builtin_amdgcn_permlane32_swap((int)A0, (int)B0, false, false);
                auto r13 = __builtin_amdgcn_permlane32_swap((int)A1, (int)B1, false, false);
                union { unsigned u[4]; bf16x8 v; } f;
                f.u[0] = (unsigned)r02[0]; f.u[1] = (unsigned)r13[0];
                f.u[2] = (unsigned)r02[1]; f.u[3] = (unsigned)r13[1];
                rfrag[ks2][pl] = f.v;
            }
        }

        // ---- GEMM2: cross[b][n] += X · Rt  (bf16x6) ----
        #pragma unroll
        for (int pa = 0; pa < 3; ++pa) {
            union { unsigned u[4]; bf16x8 v; } xfr[2][2];   // [bh][ks2]
            #pragma unroll
            for (int bh = 0; bh < 2; ++bh) {
                #pragma unroll
                for (int ks2 = 0; ks2 < 2; ++ks2) {
                    const unsigned short* xp = &Xls[pa][32 * bh + lrow][16 * ks2 + 8 * h];
                    uint2 lo = *(const uint2*)xp;
                    uint2 hi = *(const uint2*)(xp + 4);
                    xfr[bh][ks2].u[0] = lo.x; xfr[bh][ks2].u[1] = lo.y;
                    xfr[bh][ks2].u[2] = hi.x; xfr[bh][ks2].u[3] = hi.y;
                }
            }
            const int npb = 3 - pa;     // (1,1)(1,2)(1,3) (2,1)(2,2) (3,1)
            #pragma unroll
            for (int pb = 0; pb < 3; ++pb) {
                if (pb < npb) {
                    #pragma unroll
                    for (int ks2 = 0; ks2 < 2; ++ks2) {
                        acc2a = __builtin_amdgcn_mfma_f32_32x32x16_bf16(xfr[0][ks2].v, rfrag[ks2][pb], acc2a, 0, 0, 0);
                        acc2b = __builtin_amdgcn_mfma_f32_32x32x16_bf16(xfr[1][ks2].v, rfrag[ks2][pb], acc2b, 0, 0, 0);
                    }
                }
            }
        }

        // ---- periodic drain to f32 shadow (bounds acc rounding walk) ----
        if ((ch % 24) == 23) {
            sh2a += acc2a; sh2b += acc2b;
            acc2a = (f32x16)0.0f; acc2b = (f32x16)0.0f;
        }
    }

    // ---------------- epilogue: loss + argmin ----------------
    double racc_t = racc_d + __shfl_xor(racc_d, 32);
    const int nglob = n0 + 32 * nh + lrow;
    const double rk = racc_t + (double)kld[nglob];

    double lv[2][16];
    int    bi[2][16];
    #pragma unroll
    for (int bh = 0; bh < 2; ++bh)
        #pragma unroll
        for (int reg = 0; reg < 16; ++reg) {
            int bb = 32 * bh + (reg & 3) + 8 * (reg >> 2) + 4 * h;
            double cr = (double)((bh == 0) ? sh2a[reg] : sh2b[reg]);
            lv[bh][reg] = (double)xsq_s[bb] + rk - 2.0 * cr;
            bi[bh][reg] = nglob;
        }
    // butterfly min over the 32 n held across lrow lanes
    #pragma unroll
    for (int m = 1; m <= 16; m <<= 1) {
        #pragma unroll
        for (int bh = 0; bh < 2; ++bh)
            #pragma unroll
            for (int reg = 0; reg < 16; ++reg) {
                double ov = __shfl_xor(lv[bh][reg], m);
                int    oi = __shfl_xor(bi[bh][reg], m);
                if (ov < lv[bh][reg] || (ov == lv[bh][reg] && oi < bi[bh][reg])) {
                    lv[bh][reg] = ov; bi[bh][reg] = oi;
                }
            }
    }
    if (lrow == 0) {
        #pragma unroll
        for (int bh = 0; bh < 2; ++bh)
            #pragma unroll
            for (int reg = 0; reg < 16; ++reg) {
                int bb = 32 * bh + (reg & 3) + 8 * (reg >> 2) + 4 * h;
                vmin_s[nh][bb] = lv[bh][reg];
                imin_s[nh][bb] = bi[bh][reg];
            }
    }
    __syncthreads();
    if (tid < B) {
        double v0 = vmin_s[0][tid], v1 = vmin_s[1][tid];
        int    i0 = imin_s[0][tid], i1 = imin_s[1][tid];
        double bv; int bix;
        if (v1 < v0 || (v1 == v0 && i1 < i0)) { bv = v1; bix = i1; }
        else                                  { bv = v0; bix = i0; }
        pmin[((size_t)c * NBLK + nb) * B + tid] = (float)bv;
        pidx[((size_t)c * NBLK + nb) * B + tid] = bix;
    }
}

// ---------------- reduce partial mins -> logits + final idx ----------------
__global__ void reduce_kernel(const float* __restrict__ pmin, const int* __restrict__ pidx,
                              float* __restrict__ out, int* __restrict__ fidx) {
    int c = blockIdx.x, b = threadIdx.x;   // 10 blocks x 64 threads
    float bv = 3.4e38f; int bidx = 0x7fffffff;
    for (int nb = 0; nb < NBLK; ++nb) {
        float v = pmin[((size_t)c * NBLK + nb) * B + b];
        int   i = pidx[((size_t)c * NBLK + nb) * B + b];
        if (v < bv || (v == bv && i < bidx)) { bv = v; bidx = i; }
    }
    out[LOGITS_OFF + b * NC + c] = -bv;
    fidx[c * B + b] = bidx;
}

// ---------------- final: selected reconstruction + mus + logvars ----------------
__global__ __launch_bounds__(256)
void final_kernel(const float* __restrict__ zf, const float* __restrict__ dw,
                  const float* __restrict__ db, const int* __restrict__ fidx,
                  float* __restrict__ out) {
    int c = blockIdx.x >> 6;
    int b = blockIdx.x & 63;
    int t = threadIdx.x;
    int n = fidx[c * B + b];
    __shared__ float zsh[64];
    if (t < 64) zsh[t] = zf[(size_t)n * L + t];
    __syncthreads();
    const float* wcc = dw + (size_t)c * L * D;
    float* rout = out + RECS_OFF + (size_t)(c * B + b) * D;
    for (int d = t; d < D; d += 256) {
        float a = db[(size_t)c * D + d];
        #pragma unroll 8
        for (int l = 0; l < L; ++l)
            a = __builtin_fmaf(zsh[l], wcc[(size_t)l * D + d], a);
        rout[d] = 1.0f / (1.0f + __expf(-a));
    }
    if (t < 64) {
        out[MUS_OFF + (size_t)(c * B + b) * L + t] = zsh[t];
        out[LV_OFF  + (size_t)(c * B + b) * L + t] = 0.0f;
    }
}

extern "C" void kernel_launch(void* const* d_in, const int* in_sizes, int n_in,
                              void* d_out, int out_size, void* d_ws, size_t ws_size,
                              hipStream_t stream) {
    const float* xf = (const float*)d_in[0];
    const float* zf = (const float*)d_in[1];
    const float* dw = (const float*)d_in[2];
    const float* db = (const float*)d_in[3];
    float* out = (float*)d_out;
    char* ws = (char*)d_ws;

    float* kld  = (float*)(ws);              // 8000 f32
    float* xsq  = (float*)(ws + 32768);      // 64 f32
    float* pmin = (float*)(ws + 33024);      // 80000 f32
    int*   pidx = (int*)  (ws + 353024);     // 80000 i32
    int*   fidx = (int*)  (ws + 673024);     // 640 i32

    hipLaunchKernelGGL(prep_kernel, dim3(96), dim3(256), 0, stream, xf, zf, kld, xsq);
    hipLaunchKernelGGL(loss_kernel, dim3(NC * NBLK), dim3(128), 0, stream,
                       xf, zf, dw, db, kld, xsq, pmin, pidx);
    hipLaunchKernelGGL(reduce_kernel, dim3(NC), dim3(64), 0, stream, pmin, pidx, out, fidx);
    hipLaunchKernelGGL(final_kernel, dim3(NC * B), dim3(256), 0, stream, zf, dw, db, fidx, out);
}

// Round 9
// 536.550 us; speedup vs baseline: 2.3261x; 1.1347x over previous
//
#include <hip/hip_runtime.h>
#include <math.h>

#define B    64
#define D    3072
#define L    64
#define N    8000
#define NC   10
#define NT   64          // n per block
#define DC   32          // d per chunk
#define NBLK (N / NT)    // 125
#define NCH  (D / DC)    // 96

#define LOGITS_OFF 0
#define RECS_OFF   640
#define MUS_OFF    (640 + NC * B * D)          // 1,966,720
#define LV_OFF     (MUS_OFF + NC * B * L)      // 2,007,680

// workspace byte offsets
#define WSTG_OFF 0                  // 960 regions x 9216B (2 swizzled fp16 planes + 32 f32 bias + pad)
#define XSTG_OFF 8847360            // 96 regions x 8192B (2 swizzled fp16 planes)
#define KLD_OFF  9633792
#define XSQ_OFF  9665792
#define PMIN_OFF 9666048
#define PIDX_OFF 9986048
#define FIDX_OFF 10306048

#define SCALE_UP   2048.0f
#define SCALE_DN   4.8828125e-4f    // 2^-11

typedef __attribute__((ext_vector_type(8)))  _Float16 h16x8;
typedef __attribute__((ext_vector_type(16))) float    f32x16;

typedef const __attribute__((address_space(1))) unsigned int* gas1_t;
typedef __attribute__((address_space(3))) unsigned int*       las3_t;

#define MFMA16(a, b, c) __builtin_amdgcn_mfma_f32_32x32x16_f16(a, b, c, 0, 0, 0)

__device__ __forceinline__ unsigned pack2h(_Float16 lo, _Float16 hi) {
    union { _Float16 h[2]; unsigned u; } x;
    x.h[0] = lo; x.h[1] = hi;
    return x.u;
}

// ---------------- prep: split W/X into swizzled fp16 planes, kld, x_sq ----------------
__global__ __launch_bounds__(256)
void prep_kernel(const float* __restrict__ xf, const float* __restrict__ zf,
                 const float* __restrict__ dw, const float* __restrict__ db,
                 unsigned short* __restrict__ Wstg, unsigned short* __restrict__ Xstg,
                 float* __restrict__ kld, float* __restrict__ xsq) {
    const int blk = blockIdx.x, t = threadIdx.x;
    if (blk < 960) {                       // W staging for (c, ch): transpose + split + swizzle
        const int c = blk / 96, ch = blk % 96;
        __shared__ float wt[32][68];
        #pragma unroll
        for (int k = 0; k < 8; ++k) {
            int l = (t >> 5) + 8 * k;      // 0..63
            int d = t & 31;
            wt[d][l] = dw[(size_t)(c * 64 + l) * D + ch * 32 + d];
        }
        __syncthreads();
        const int d = t >> 3, lg = t & 7, l0 = lg * 8;
        float v[8];
        *(float4*)&v[0] = *(const float4*)&wt[d][l0];
        *(float4*)&v[4] = *(const float4*)&wt[d][l0 + 4];
        _Float16 p1[8], p2[8];
        #pragma unroll
        for (int j = 0; j < 8; ++j) {
            p1[j] = (_Float16)v[j];
            p2[j] = (_Float16)((v[j] - (float)p1[j]) * SCALE_UP);
        }
        unsigned short* reg = Wstg + (size_t)blk * 4608;   // 9216B region
        const int slot = lg ^ (d & 7);
        *(uint4*)&reg[d * 64 + slot * 8]        = *(const uint4*)&p1[0];
        *(uint4*)&reg[2048 + d * 64 + slot * 8] = *(const uint4*)&p2[0];
        if (t < 32) ((float*)(reg + 4096))[t] = db[(size_t)c * D + ch * 32 + t];
    } else if (blk < 1056) {               // X staging for ch: split + swizzle
        const int ch = blk - 960;
        const int b = t >> 2, dg = t & 3, dl0 = dg * 8;
        float v[8];
        *(float4*)&v[0] = *(const float4*)&xf[(size_t)b * D + ch * 32 + dl0];
        *(float4*)&v[4] = *(const float4*)&xf[(size_t)b * D + ch * 32 + dl0 + 4];
        _Float16 p1[8], p2[8];
        #pragma unroll
        for (int j = 0; j < 8; ++j) {
            p1[j] = (_Float16)v[j];
            p2[j] = (_Float16)((v[j] - (float)p1[j]) * SCALE_UP);
        }
        unsigned short* reg = Xstg + (size_t)ch * 4096;    // 8192B region
        const int slot = dg ^ (b & 3);
        *(uint4*)&reg[b * 32 + slot * 8]        = *(const uint4*)&p1[0];
        *(uint4*)&reg[2048 + b * 32 + slot * 8] = *(const uint4*)&p2[0];
    } else if (blk < 1088) {               // kld[n] = 0.5*||z_n||^2
        int n = (blk - 1056) * 256 + t;
        if (n < N) {
            const float4* zp = (const float4*)(zf + (size_t)n * L);
            float s = 0.f;
            #pragma unroll
            for (int k = 0; k < 16; ++k) {
                float4 v4 = zp[k];
                s += v4.x * v4.x + v4.y * v4.y + v4.z * v4.z + v4.w * v4.w;
            }
            kld[n] = 0.5f * s;
        }
    } else {                               // xsq[b], blocks 1088..1151
        int b = blk - 1088;
        float s = 0.f;
        #pragma unroll
        for (int k = 0; k < 12; ++k) {
            float v = xf[(size_t)b * D + k * 256 + t];
            s = __builtin_fmaf(v, v, s);
        }
        for (int m = 1; m < 64; m <<= 1) s += __shfl_xor(s, m);
        __shared__ float ps[4];
        if ((t & 63) == 0) ps[t >> 6] = s;
        __syncthreads();
        if (t == 0) xsq[b] = ps[0] + ps[1] + ps[2] + ps[3];
    }
}

// ---------------- main: fp16 split MFMA fused loss ----------------
__global__ __launch_bounds__(128, 2)
void loss_kernel(const unsigned short* __restrict__ Wstg, const unsigned short* __restrict__ Xstg,
                 const float* __restrict__ zf, const float* __restrict__ kld,
                 const float* __restrict__ xsq,
                 float* __restrict__ pmin, int* __restrict__ pidx) {
    const int tid  = threadIdx.x;
    const int nh   = tid >> 6;      // wave id = n-half
    const int lane = tid & 63;
    const int lrow = lane & 31;
    const int h    = lane >> 5;

    // bijective XCD swizzle (nwg=1250, 8 XCDs: q=156, r=2)
    int bid = blockIdx.x;
    {
        int xcd = bid & 7, idx = bid >> 3;
        bid = (xcd < 2 ? xcd * 157 : 2 * 157 + (xcd - 2) * 156) + idx;
    }
    const int c  = bid / NBLK;
    const int nb = bid % NBLK;
    const int n0 = nb * NT;

    __shared__ __align__(16) unsigned char stg[2][17408];  // [buf]: [0,9216)=W+bias, [9216,17408)=X
    __shared__ float  xsq_s[B];
    __shared__ double vmin_s[2][B];
    __shared__ int    imin_s[2][B];

    // ---- Z fragments: fp16 2-plane (plane1 scaled x2048) ----
    h16x8 zfrag[4][2];
    {
        const float* zr = zf + (size_t)(n0 + 32 * nh + lrow) * L;
        #pragma unroll
        for (int ks = 0; ks < 4; ++ks) {
            float4 za = *(const float4*)(zr + ks * 16 + h * 8);
            float4 zb = *(const float4*)(zr + ks * 16 + h * 8 + 4);
            float vv[8] = {za.x, za.y, za.z, za.w, zb.x, zb.y, zb.z, zb.w};
            #pragma unroll
            for (int e = 0; e < 8; ++e) {
                _Float16 a1 = (_Float16)vv[e];
                zfrag[ks][0][e] = a1;
                zfrag[ks][1][e] = (_Float16)((vv[e] - (float)a1) * SCALE_UP);
            }
        }
    }
    if (tid < B) xsq_s[tid] = xsq[tid];

    const char* wsrc = (const char*)(Wstg + (size_t)(c * 96) * 4608);
    const char* xsrc = (const char*)Xstg;

#define STAGE(buf_, ch_)  do {                                                          \
        if (nh == 0) {                                                                  \
            const char* g_ = wsrc + (size_t)(ch_) * 9216 + lane * 16;                   \
            char* l_ = (char*)&stg[buf_][0];                                            \
            _Pragma("unroll")                                                           \
            for (int i_ = 0; i_ < 9; ++i_)                                              \
                __builtin_amdgcn_global_load_lds((gas1_t)(g_ + i_ * 1024),              \
                                                 (las3_t)(l_ + i_ * 1024), 16, 0, 0);   \
        } else {                                                                        \
            const char* g_ = xsrc + (size_t)(ch_) * 8192 + lane * 16;                   \
            char* l_ = (char*)&stg[buf_][9216];                                         \
            _Pragma("unroll")                                                           \
            for (int i_ = 0; i_ < 8; ++i_)                                              \
                __builtin_amdgcn_global_load_lds((gas1_t)(g_ + i_ * 1024),              \
                                                 (las3_t)(l_ + i_ * 1024), 16, 0, 0);   \
        } } while (0)

    // precomputed swizzled LDS byte offsets (loop-invariant)
    int woff[4];
    #pragma unroll
    for (int ks = 0; ks < 4; ++ks)
        woff[ks] = lrow * 128 + (((2 * ks + h) ^ (lrow & 7)) << 4);
    int xoff[2][2];
    #pragma unroll
    for (int bh = 0; bh < 2; ++bh)
        #pragma unroll
        for (int ks2 = 0; ks2 < 2; ++ks2) {
            int b = 32 * bh + lrow;
            xoff[bh][ks2] = b * 64 + (((2 * ks2 + h) ^ (b & 3)) << 4);
        }

    f32x16 acc2a = (f32x16)0.0f, acc2b = (f32x16)0.0f;   // main plane cross
    f32x16 accca = (f32x16)0.0f, acccb = (f32x16)0.0f;   // correction (scaled x2048)
    f32x16 sh2a  = (f32x16)0.0f, sh2b  = (f32x16)0.0f;   // f32 shadow of main
    double racc_d = 0.0;

    STAGE(0, 0);
    __syncthreads();                     // drains vmcnt: buf0 staged

    int buf = 0;
    for (int ch = 0; ch < NCH; ++ch) {
        if (ch + 1 < NCH) STAGE(buf ^ 1, ch + 1);

        const unsigned char* base = &stg[buf][0];

        // ---- GEMM1: rt(main) = w1*z1 ; rtc(corr) = w1*z2' + w2'*z1 ----
        f32x16 rt  = (f32x16)0.0f;
        f32x16 rtc = (f32x16)0.0f;
        #pragma unroll
        for (int ks = 0; ks < 4; ++ks) {
            h16x8 w1 = *(const h16x8*)(base + woff[ks]);
            h16x8 w2 = *(const h16x8*)(base + 4096 + woff[ks]);
            rt  = MFMA16(w1, zfrag[ks][0], rt);
            rtc = MFMA16(w1, zfrag[ks][1], rtc);
            rtc = MFMA16(w2, zfrag[ks][0], rtc);
        }

        const float* biasb = (const float*)(base + 8192);
        float4 bq[4];
        #pragma unroll
        for (int q = 0; q < 4; ++q) bq[q] = *(const float4*)&biasb[8 * q + 4 * h];

        // ---- sigmoid + r^2 ----
        float sv[16];
        float ch_r2 = 0.f;
        #pragma unroll
        for (int r_ = 0; r_ < 16; ++r_) {
            float a = __builtin_fmaf(rtc[r_], SCALE_DN, rt[r_]) + bq[r_ >> 2][r_ & 3];
            float r = 1.0f / (1.0f + __expf(-a));
            sv[r_] = r;
            ch_r2 = __builtin_fmaf(r, r, ch_r2);
        }
        racc_d += (double)ch_r2;

        // ---- build GEMM2 B-fragments (fp16 2-plane, permlane redistribution) ----
        h16x8 rfrag[2][2];
        #pragma unroll
        for (int ks2 = 0; ks2 < 2; ++ks2) {
            _Float16 p1[8], p2[8];
            #pragma unroll
            for (int e = 0; e < 8; ++e) {
                float v = sv[8 * ks2 + e];
                _Float16 a1 = (_Float16)v;
                p1[e] = a1;
                p2[e] = (_Float16)((v - (float)a1) * SCALE_UP);
            }
            #pragma unroll
            for (int pl = 0; pl < 2; ++pl) {
                const _Float16* sp = pl ? p2 : p1;
                unsigned A0 = pack2h(sp[0], sp[1]), A1 = pack2h(sp[2], sp[3]);
                unsigned B0 = pack2h(sp[4], sp[5]), B1 = pack2h(sp[6], sp[7]);
                auto r02 = __builtin_amdgcn_permlane32_swap((int)A0, (int)B0, false, false);
                auto r13 = __builtin_amdgcn_permlane32_swap((int)A1, (int)B1, false, false);
                union { unsigned u[4]; h16x8 v; } f;
                f.u[0] = (unsigned)r02[0]; f.u[1] = (unsigned)r13[0];
                f.u[2] = (unsigned)r02[1]; f.u[3] = (unsigned)r13[1];
                rfrag[ks2][pl] = f.v;
            }
        }

        // ---- GEMM2: main x1*r1 ; corr x1*r2' + x2'*r1 ----
        const unsigned char* xb = base + 9216;
        #pragma unroll
        for (int ks2 = 0; ks2 < 2; ++ks2) {
            h16x8 x1a = *(const h16x8*)(xb + xoff[0][ks2]);
            h16x8 x1b = *(const h16x8*)(xb + xoff[1][ks2]);
            h16x8 x2a = *(const h16x8*)(xb + 4096 + xoff[0][ks2]);
            h16x8 x2b = *(const h16x8*)(xb + 4096 + xoff[1][ks2]);
            acc2a = MFMA16(x1a, rfrag[ks2][0], acc2a);
            acc2b = MFMA16(x1b, rfrag[ks2][0], acc2b);
            accca = MFMA16(x1a, rfrag[ks2][1], accca);
            acccb = MFMA16(x1b, rfrag[ks2][1], acccb);
            accca = MFMA16(x2a, rfrag[ks2][0], accca);
            acccb = MFMA16(x2b, rfrag[ks2][0], acccb);
        }

        if ((ch & 31) == 31) {           // shadow drain: bounds f32 acc rounding walk
            sh2a += acc2a; sh2b += acc2b;
            acc2a = (f32x16)0.0f; acc2b = (f32x16)0.0f;
        }

        __syncthreads();                 // drains prefetch vmcnt + protects buf reuse
        buf ^= 1;
    }
    sh2a += acc2a; sh2b += acc2b;

    // ---------------- epilogue: loss + argmin ----------------
    double racc_t = racc_d + __shfl_xor(racc_d, 32);
    const int nglob = n0 + 32 * nh + lrow;
    const double rk = racc_t + (double)kld[nglob];

    double lv[2][16];
    int    bi[2][16];
    #pragma unroll
    for (int bh = 0; bh < 2; ++bh)
        #pragma unroll
        for (int r_ = 0; r_ < 16; ++r_) {
            int bb = 32 * bh + (r_ & 3) + 8 * (r_ >> 2) + 4 * h;
            double cr = (bh == 0)
                ? ((double)sh2a[r_] + (double)accca[r_] * (double)SCALE_DN)
                : ((double)sh2b[r_] + (double)acccb[r_] * (double)SCALE_DN);
            lv[bh][r_] = (double)xsq_s[bb] + rk - 2.0 * cr;
            bi[bh][r_] = nglob;
        }
    #pragma unroll
    for (int m = 1; m <= 16; m <<= 1) {
        #pragma unroll
        for (int bh = 0; bh < 2; ++bh)
            #pragma unroll
            for (int r_ = 0; r_ < 16; ++r_) {
                double ov = __shfl_xor(lv[bh][r_], m);
                int    oi = __shfl_xor(bi[bh][r_], m);
                if (ov < lv[bh][r_] || (ov == lv[bh][r_] && oi < bi[bh][r_])) {
                    lv[bh][r_] = ov; bi[bh][r_] = oi;
                }
            }
    }
    if (lrow == 0) {
        #pragma unroll
        for (int bh = 0; bh < 2; ++bh)
            #pragma unroll
            for (int r_ = 0; r_ < 16; ++r_) {
                int bb = 32 * bh + (r_ & 3) + 8 * (r_ >> 2) + 4 * h;
                vmin_s[nh][bb] = lv[bh][r_];
                imin_s[nh][bb] = bi[bh][r_];
            }
    }
    __syncthreads();
    if (tid < B) {
        double v0 = vmin_s[0][tid], v1 = vmin_s[1][tid];
        int    i0 = imin_s[0][tid], i1 = imin_s[1][tid];
        double bv; int bix;
        if (v1 < v0 || (v1 == v0 && i1 < i0)) { bv = v1; bix = i1; }
        else                                  { bv = v0; bix = i0; }
        pmin[((size_t)c * NBLK + nb) * B + tid] = (float)bv;
        pidx[((size_t)c * NBLK + nb) * B + tid] = bix;
    }
#undef STAGE
}

// ---------------- reduce partial mins -> logits + final idx ----------------
__global__ void reduce_kernel(const float* __restrict__ pmin, const int* __restrict__ pidx,
                              float* __restrict__ out, int* __restrict__ fidx) {
    int c = blockIdx.x, b = threadIdx.x;   // 10 blocks x 64 threads
    float bv = 3.4e38f; int bidx = 0x7fffffff;
    for (int nb = 0; nb < NBLK; ++nb) {
        float v = pmin[((size_t)c * NBLK + nb) * B + b];
        int   i = pidx[((size_t)c * NBLK + nb) * B + b];
        if (v < bv || (v == bv && i < bidx)) { bv = v; bidx = i; }
    }
    out[LOGITS_OFF + b * NC + c] = -bv;
    fidx[c * B + b] = bidx;
}

// ---------------- final: selected reconstruction + mus + logvars ----------------
__global__ __launch_bounds__(256)
void final_kernel(const float* __restrict__ zf, const float* __restrict__ dw,
                  const float* __restrict__ db, const int* __restrict__ fidx,
                  float* __restrict__ out) {
    int c = blockIdx.x >> 6;
    int b = blockIdx.x & 63;
    int t = threadIdx.x;
    int n = fidx[c * B + b];
    __shared__ float zsh[64];
    if (t < 64) zsh[t] = zf[(size_t)n * L + t];
    __syncthreads();
    const float* wcc = dw + (size_t)c * L * D;
    float* rout = out + RECS_OFF + (size_t)(c * B + b) * D;
    for (int d = t; d < D; d += 256) {
        float a = db[(size_t)c * D + d];
        #pragma unroll 8
        for (int l = 0; l < L; ++l)
            a = __builtin_fmaf(zsh[l], wcc[(size_t)l * D + d], a);
        rout[d] = 1.0f / (1.0f + __expf(-a));
    }
    if (t < 64) {
        out[MUS_OFF + (size_t)(c * B + b) * L + t] = zsh[t];
        out[LV_OFF  + (size_t)(c * B + b) * L + t] = 0.0f;
    }
}

extern "C" void kernel_launch(void* const* d_in, const int* in_sizes, int n_in,
                              void* d_out, int out_size, void* d_ws, size_t ws_size,
                              hipStream_t stream) {
    const float* xf = (const float*)d_in[0];
    const float* zf = (const float*)d_in[1];
    const float* dw = (const float*)d_in[2];
    const float* db = (const float*)d_in[3];
    float* out = (float*)d_out;
    char* ws = (char*)d_ws;

    unsigned short* Wstg = (unsigned short*)(ws + WSTG_OFF);
    unsigned short* Xstg = (unsigned short*)(ws + XSTG_OFF);
    float* kld  = (float*)(ws + KLD_OFF);
    float* xsq  = (float*)(ws + XSQ_OFF);
    float* pmin = (float*)(ws + PMIN_OFF);
    int*   pidx = (int*)  (ws + PIDX_OFF);
    int*   fidx = (int*)  (ws + FIDX_OFF);

    hipLaunchKernelGGL(prep_kernel, dim3(1152), dim3(256), 0, stream,
                       xf, zf, dw, db, Wstg, Xstg, kld, xsq);
    hipLaunchKernelGGL(loss_kernel, dim3(NC * NBLK), dim3(128), 0, stream,
                       Wstg, Xstg, zf, kld, xsq, pmin, pidx);
    hipLaunchKernelGGL(reduce_kernel, dim3(NC), dim3(64), 0, stream, pmin, pidx, out, fidx);
    hipLaunchKernelGGL(final_kernel, dim3(NC * B), dim3(256), 0, stream, zf, dw, db, fidx, out);
}

// Round 10
// 422.566 us; speedup vs baseline: 2.9536x; 1.2697x over previous
//
#include <hip/hip_runtime.h>
#include <math.h>

#define B    64
#define D    3072
#define L    64
#define N    8000
#define NC   10
#define NT   64          // n per block
#define DC   32          // d per chunk
#define NBLK (N / NT)    // 125
#define NCH  (D / DC)    // 96

#define LOGITS_OFF 0
#define RECS_OFF   640
#define MUS_OFF    (640 + NC * B * D)          // 1,966,720
#define LV_OFF     (MUS_OFF + NC * B * L)      // 2,007,680

// workspace byte offsets
#define WSTG_OFF 0                  // 960 regions x 9216B: [plane(4096)][lslot(512)][d(16)] + bias@8192
#define XSTG_OFF 8847360            // 96 regions x 8192B: [plane(4096)][dslot(1024)][b(16)]
#define KLD_OFF  9633792
#define XSQ_OFF  9665792
#define PMIN_OFF 9666048
#define PIDX_OFF 9986048
#define FIDX_OFF 10306048

#define SCALE_UP   2048.0f
#define SCALE_DN   4.8828125e-4f    // 2^-11

typedef __attribute__((ext_vector_type(8)))  _Float16 h16x8;
typedef __attribute__((ext_vector_type(16))) float    f32x16;

typedef const __attribute__((address_space(1))) unsigned int* gas1_t;
typedef __attribute__((address_space(3))) unsigned int*       las3_t;

#define MFMA16(a, b, c) __builtin_amdgcn_mfma_f32_32x32x16_f16(a, b, c, 0, 0, 0)

__device__ __forceinline__ unsigned pack2h(_Float16 lo, _Float16 hi) {
    union { _Float16 h[2]; unsigned u; } x;
    x.h[0] = lo; x.h[1] = hi;
    return x.u;
}

// ---------------- prep: split W/X into slot-major fp16 planes, kld, x_sq ----------------
__global__ __launch_bounds__(256)
void prep_kernel(const float* __restrict__ xf, const float* __restrict__ zf,
                 const float* __restrict__ dw, const float* __restrict__ db,
                 unsigned short* __restrict__ Wstg, unsigned short* __restrict__ Xstg,
                 float* __restrict__ kld, float* __restrict__ xsq) {
    const int blk = blockIdx.x, t = threadIdx.x;
    if (blk < 960) {                       // W staging for (c, ch): transpose + split, slot-major
        const int c = blk / 96, ch = blk % 96;
        __shared__ float wt[32][68];
        #pragma unroll
        for (int k = 0; k < 8; ++k) {
            int l = (t >> 5) + 8 * k;      // 0..63
            int d = t & 31;
            wt[d][l] = dw[(size_t)(c * 64 + l) * D + ch * 32 + d];
        }
        __syncthreads();
        const int d = t >> 3, lg = t & 7, l0 = lg * 8;   // lg = l-slot
        float v[8];
        *(float4*)&v[0] = *(const float4*)&wt[d][l0];
        *(float4*)&v[4] = *(const float4*)&wt[d][l0 + 4];
        _Float16 p1[8], p2[8];
        #pragma unroll
        for (int j = 0; j < 8; ++j) {
            p1[j] = (_Float16)v[j];
            p2[j] = (_Float16)((v[j] - (float)p1[j]) * SCALE_UP);
        }
        unsigned short* reg = Wstg + (size_t)blk * 4608;   // 9216B region
        // slot-major: byte = plane*4096 + lg*512 + d*16  (16B-aligned, conflict-free reads)
        *(uint4*)&reg[lg * 256 + d * 8]        = *(const uint4*)&p1[0];
        *(uint4*)&reg[2048 + lg * 256 + d * 8] = *(const uint4*)&p2[0];
        if (t < 32) ((float*)(reg + 4096))[t] = db[(size_t)c * D + ch * 32 + t];
    } else if (blk < 1056) {               // X staging for ch: split, slot-major
        const int ch = blk - 960;
        const int b = t >> 2, dg = t & 3, dl0 = dg * 8;  // dg = d-slot
        float v[8];
        *(float4*)&v[0] = *(const float4*)&xf[(size_t)b * D + ch * 32 + dl0];
        *(float4*)&v[4] = *(const float4*)&xf[(size_t)b * D + ch * 32 + dl0 + 4];
        _Float16 p1[8], p2[8];
        #pragma unroll
        for (int j = 0; j < 8; ++j) {
            p1[j] = (_Float16)v[j];
            p2[j] = (_Float16)((v[j] - (float)p1[j]) * SCALE_UP);
        }
        unsigned short* reg = Xstg + (size_t)ch * 4096;    // 8192B region
        // slot-major: byte = plane*4096 + dg*1024 + b*16
        *(uint4*)&reg[dg * 512 + b * 8]        = *(const uint4*)&p1[0];
        *(uint4*)&reg[2048 + dg * 512 + b * 8] = *(const uint4*)&p2[0];
    } else if (blk < 1088) {               // kld[n] = 0.5*||z_n||^2
        int n = (blk - 1056) * 256 + t;
        if (n < N) {
            const float4* zp = (const float4*)(zf + (size_t)n * L);
            float s = 0.f;
            #pragma unroll
            for (int k = 0; k < 16; ++k) {
                float4 v4 = zp[k];
                s += v4.x * v4.x + v4.y * v4.y + v4.z * v4.z + v4.w * v4.w;
            }
            kld[n] = 0.5f * s;
        }
    } else {                               // xsq[b], blocks 1088..1151
        int b = blk - 1088;
        float s = 0.f;
        #pragma unroll
        for (int k = 0; k < 12; ++k) {
            float v = xf[(size_t)b * D + k * 256 + t];
            s = __builtin_fmaf(v, v, s);
        }
        for (int m = 1; m < 64; m <<= 1) s += __shfl_xor(s, m);
        __shared__ float ps[4];
        if ((t & 63) == 0) ps[t >> 6] = s;
        __syncthreads();
        if (t == 0) xsq[b] = ps[0] + ps[1] + ps[2] + ps[3];
    }
}

// ---------------- main: fp16 split MFMA fused loss ----------------
__global__ __launch_bounds__(128, 2)
void loss_kernel(const unsigned short* __restrict__ Wstg, const unsigned short* __restrict__ Xstg,
                 const float* __restrict__ zf, const float* __restrict__ kld,
                 const float* __restrict__ xsq,
                 float* __restrict__ pmin, int* __restrict__ pidx) {
    const int tid  = threadIdx.x;
    const int nh   = tid >> 6;      // wave id = n-half
    const int lane = tid & 63;
    const int lrow = lane & 31;
    const int h    = lane >> 5;

    // bijective XCD swizzle (nwg=1250, 8 XCDs: q=156, r=2)
    int bid = blockIdx.x;
    {
        int xcd = bid & 7, idx = bid >> 3;
        bid = (xcd < 2 ? xcd * 157 : 2 * 157 + (xcd - 2) * 156) + idx;
    }
    const int c  = bid / NBLK;
    const int nb = bid % NBLK;
    const int n0 = nb * NT;

    __shared__ __align__(16) unsigned char stg[2][17408];  // [buf]: [0,9216)=W+bias, [9216,17408)=X
    __shared__ float  xsq_s[B];
    __shared__ double vmin_s[2][B];
    __shared__ int    imin_s[2][B];

    // ---- Z fragments: fp16 2-plane (plane1 scaled x2048) ----
    h16x8 zfrag[4][2];
    {
        const float* zr = zf + (size_t)(n0 + 32 * nh + lrow) * L;
        #pragma unroll
        for (int ks = 0; ks < 4; ++ks) {
            float4 za = *(const float4*)(zr + ks * 16 + h * 8);
            float4 zb = *(const float4*)(zr + ks * 16 + h * 8 + 4);
            float vv[8] = {za.x, za.y, za.z, za.w, zb.x, zb.y, zb.z, zb.w};
            #pragma unroll
            for (int e = 0; e < 8; ++e) {
                _Float16 a1 = (_Float16)vv[e];
                zfrag[ks][0][e] = a1;
                zfrag[ks][1][e] = (_Float16)((vv[e] - (float)a1) * SCALE_UP);
            }
        }
    }
    if (tid < B) xsq_s[tid] = xsq[tid];

    const char* wsrc = (const char*)(Wstg + (size_t)(c * 96) * 4608);
    const char* xsrc = (const char*)Xstg;

#define STAGE(buf_, ch_)  do {                                                          \
        if (nh == 0) {                                                                  \
            const char* g_ = wsrc + (size_t)(ch_) * 9216 + lane * 16;                   \
            char* l_ = (char*)&stg[buf_][0];                                            \
            _Pragma("unroll")                                                           \
            for (int i_ = 0; i_ < 9; ++i_)                                              \
                __builtin_amdgcn_global_load_lds((gas1_t)(g_ + i_ * 1024),              \
                                                 (las3_t)(l_ + i_ * 1024), 16, 0, 0);   \
        } else {                                                                        \
            const char* g_ = xsrc + (size_t)(ch_) * 8192 + lane * 16;                   \
            char* l_ = (char*)&stg[buf_][9216];                                         \
            _Pragma("unroll")                                                           \
            for (int i_ = 0; i_ < 8; ++i_)                                              \
                __builtin_amdgcn_global_load_lds((gas1_t)(g_ + i_ * 1024),              \
                                                 (las3_t)(l_ + i_ * 1024), 16, 0, 0);   \
        } } while (0)

    // slot-major LDS byte offsets: addr = slot*stride + lane_row*16 (contiguous per half-wave)
    int woff[4];
    #pragma unroll
    for (int ks = 0; ks < 4; ++ks)
        woff[ks] = (2 * ks + h) * 512 + lrow * 16;
    int xoff[2][2];
    #pragma unroll
    for (int bh = 0; bh < 2; ++bh)
        #pragma unroll
        for (int ks2 = 0; ks2 < 2; ++ks2)
            xoff[bh][ks2] = (2 * ks2 + h) * 1024 + (32 * bh + lrow) * 16;

    f32x16 acc2a = (f32x16)0.0f, acc2b = (f32x16)0.0f;   // main plane cross
    f32x16 accca = (f32x16)0.0f, acccb = (f32x16)0.0f;   // correction via X plane2 (scaled x2048)
    f32x16 sh2a  = (f32x16)0.0f, sh2b  = (f32x16)0.0f;   // f32 shadow of main
    double racc_d = 0.0;

    STAGE(0, 0);
    __syncthreads();                     // drains vmcnt: buf0 staged

    int buf = 0;
    for (int ch = 0; ch < NCH; ++ch) {
        if (ch + 1 < NCH) STAGE(buf ^ 1, ch + 1);

        const unsigned char* base = &stg[buf][0];

        // ---- GEMM1: rt(main) = w1*z1 ; rtc(corr) = w1*z2' + w2'*z1 ----
        f32x16 rt  = (f32x16)0.0f;
        f32x16 rtc = (f32x16)0.0f;
        #pragma unroll
        for (int ks = 0; ks < 4; ++ks) {
            h16x8 w1 = *(const h16x8*)(base + woff[ks]);
            h16x8 w2 = *(const h16x8*)(base + 4096 + woff[ks]);
            rt  = MFMA16(w1, zfrag[ks][0], rt);
            rtc = MFMA16(w1, zfrag[ks][1], rtc);
            rtc = MFMA16(w2, zfrag[ks][0], rtc);
        }

        const float* biasb = (const float*)(base + 8192);
        float4 bq[4];
        #pragma unroll
        for (int q = 0; q < 4; ++q) bq[q] = *(const float4*)&biasb[8 * q + 4 * h];

        // ---- sigmoid + r^2 (raw v_rcp: 1-instr reciprocal, ~1ulp) ----
        float sv[16];
        float ch_r2 = 0.f;
        #pragma unroll
        for (int r_ = 0; r_ < 16; ++r_) {
            float a = __builtin_fmaf(rtc[r_], SCALE_DN, rt[r_]) + bq[r_ >> 2][r_ & 3];
            float r = __builtin_amdgcn_rcpf(1.0f + __expf(-a));
            sv[r_] = r;
            ch_r2 = __builtin_fmaf(r, r, ch_r2);
        }
        racc_d += (double)ch_r2;

        // ---- build GEMM2 B-fragments (single fp16 plane, permlane redistribution) ----
        h16x8 rfrag[2];
        #pragma unroll
        for (int ks2 = 0; ks2 < 2; ++ks2) {
            _Float16 p1[8];
            #pragma unroll
            for (int e = 0; e < 8; ++e)
                p1[e] = (_Float16)sv[8 * ks2 + e];
            unsigned A0 = pack2h(p1[0], p1[1]), A1 = pack2h(p1[2], p1[3]);
            unsigned B0 = pack2h(p1[4], p1[5]), B1 = pack2h(p1[6], p1[7]);
            auto r02 = __builtin_amdgcn_permlane32_swap((int)A0, (int)B0, false, false);
            auto r13 = __builtin_amdgcn_permlane32_swap((int)A1, (int)B1, false, false);
            union { unsigned u[4]; h16x8 v; } f;
            f.u[0] = (unsigned)r02[0]; f.u[1] = (unsigned)r13[0];
            f.u[2] = (unsigned)r02[1]; f.u[3] = (unsigned)r13[1];
            rfrag[ks2] = f.v;
        }

        // ---- GEMM2: main x1*r1 ; corr x2'*r1 (X plane2 carries the correction) ----
        const unsigned char* xb = base + 9216;
        #pragma unroll
        for (int ks2 = 0; ks2 < 2; ++ks2) {
            h16x8 x1a = *(const h16x8*)(xb + xoff[0][ks2]);
            h16x8 x1b = *(const h16x8*)(xb + xoff[1][ks2]);
            h16x8 x2a = *(const h16x8*)(xb + 4096 + xoff[0][ks2]);
            h16x8 x2b = *(const h16x8*)(xb + 4096 + xoff[1][ks2]);
            acc2a = MFMA16(x1a, rfrag[ks2], acc2a);
            acc2b = MFMA16(x1b, rfrag[ks2], acc2b);
            accca = MFMA16(x2a, rfrag[ks2], accca);
            acccb = MFMA16(x2b, rfrag[ks2], acccb);
        }

        if ((ch & 31) == 31) {           // shadow drain: bounds f32 acc rounding walk
            sh2a += acc2a; sh2b += acc2b;
            acc2a = (f32x16)0.0f; acc2b = (f32x16)0.0f;
        }

        __syncthreads();                 // drains prefetch vmcnt + protects buf reuse
        buf ^= 1;
    }
    sh2a += acc2a; sh2b += acc2b;

    // ---------------- epilogue: loss + argmin ----------------
    double racc_t = racc_d + __shfl_xor(racc_d, 32);
    const int nglob = n0 + 32 * nh + lrow;
    const double rk = racc_t + (double)kld[nglob];

    double lv[2][16];
    int    bi[2][16];
    #pragma unroll
    for (int bh = 0; bh < 2; ++bh)
        #pragma unroll
        for (int r_ = 0; r_ < 16; ++r_) {
            int bb = 32 * bh + (r_ & 3) + 8 * (r_ >> 2) + 4 * h;
            double cr = (bh == 0)
                ? ((double)sh2a[r_] + (double)accca[r_] * (double)SCALE_DN)
                : ((double)sh2b[r_] + (double)acccb[r_] * (double)SCALE_DN);
            lv[bh][r_] = (double)xsq_s[bb] + rk - 2.0 * cr;
            bi[bh][r_] = nglob;
        }
    #pragma unroll
    for (int m = 1; m <= 16; m <<= 1) {
        #pragma unroll
        for (int bh = 0; bh < 2; ++bh)
            #pragma unroll
            for (int r_ = 0; r_ < 16; ++r_) {
                double ov = __shfl_xor(lv[bh][r_], m);
                int    oi = __shfl_xor(bi[bh][r_], m);
                if (ov < lv[bh][r_] || (ov == lv[bh][r_] && oi < bi[bh][r_])) {
                    lv[bh][r_] = ov; bi[bh][r_] = oi;
                }
            }
    }
    if (lrow == 0) {
        #pragma unroll
        for (int bh = 0; bh < 2; ++bh)
            #pragma unroll
            for (int r_ = 0; r_ < 16; ++r_) {
                int bb = 32 * bh + (r_ & 3) + 8 * (r_ >> 2) + 4 * h;
                vmin_s[nh][bb] = lv[bh][r_];
                imin_s[nh][bb] = bi[bh][r_];
            }
    }
    __syncthreads();
    if (tid < B) {
        double v0 = vmin_s[0][tid], v1 = vmin_s[1][tid];
        int    i0 = imin_s[0][tid], i1 = imin_s[1][tid];
        double bv; int bix;
        if (v1 < v0 || (v1 == v0 && i1 < i0)) { bv = v1; bix = i1; }
        else                                  { bv = v0; bix = i0; }
        pmin[((size_t)c * NBLK + nb) * B + tid] = (float)bv;
        pidx[((size_t)c * NBLK + nb) * B + tid] = bix;
    }
#undef STAGE
}

// ---------------- reduce partial mins -> logits + final idx ----------------
__global__ void reduce_kernel(const float* __restrict__ pmin, const int* __restrict__ pidx,
                              float* __restrict__ out, int* __restrict__ fidx) {
    int c = blockIdx.x, b = threadIdx.x;   // 10 blocks x 64 threads
    float bv = 3.4e38f; int bidx = 0x7fffffff;
    for (int nb = 0; nb < NBLK; ++nb) {
        float v = pmin[((size_t)c * NBLK + nb) * B + b];
        int   i = pidx[((size_t)c * NBLK + nb) * B + b];
        if (v < bv || (v == bv && i < bidx)) { bv = v; bidx = i; }
    }
    out[LOGITS_OFF + b * NC + c] = -bv;
    fidx[c * B + b] = bidx;
}

// ---------------- final: selected reconstruction + mus + logvars ----------------
__global__ __launch_bounds__(256)
void final_kernel(const float* __restrict__ zf, const float* __restrict__ dw,
                  const float* __restrict__ db, const int* __restrict__ fidx,
                  float* __restrict__ out) {
    int c = blockIdx.x >> 6;
    int b = blockIdx.x & 63;
    int t = threadIdx.x;
    int n = fidx[c * B + b];
    __shared__ float zsh[64];
    if (t < 64) zsh[t] = zf[(size_t)n * L + t];
    __syncthreads();
    const float* wcc = dw + (size_t)c * L * D;
    float* rout = out + RECS_OFF + (size_t)(c * B + b) * D;
    for (int d = t; d < D; d += 256) {
        float a = db[(size_t)c * D + d];
        #pragma unroll 8
        for (int l = 0; l < L; ++l)
            a = __builtin_fmaf(zsh[l], wcc[(size_t)l * D + d], a);
        rout[d] = 1.0f / (1.0f + __expf(-a));
    }
    if (t < 64) {
        out[MUS_OFF + (size_t)(c * B + b) * L + t] = zsh[t];
        out[LV_OFF  + (size_t)(c * B + b) * L + t] = 0.0f;
    }
}

extern "C" void kernel_launch(void* const* d_in, const int* in_sizes, int n_in,
                              void* d_out, int out_size, void* d_ws, size_t ws_size,
                              hipStream_t stream) {
    const float* xf = (const float*)d_in[0];
    const float* zf = (const float*)d_in[1];
    const float* dw = (const float*)d_in[2];
    const float* db = (const float*)d_in[3];
    float* out = (float*)d_out;
    char* ws = (char*)d_ws;

    unsigned short* Wstg = (unsigned short*)(ws + WSTG_OFF);
    unsigned short* Xstg = (unsigned short*)(ws + XSTG_OFF);
    float* kld  = (float*)(ws + KLD_OFF);
    float* xsq  = (float*)(ws + XSQ_OFF);
    float* pmin = (float*)(ws + PMIN_OFF);
    int*   pidx = (int*)  (ws + PIDX_OFF);
    int*   fidx = (int*)  (ws + FIDX_OFF);

    hipLaunchKernelGGL(prep_kernel, dim3(1152), dim3(256), 0, stream,
                       xf, zf, dw, db, Wstg, Xstg, kld, xsq);
    hipLaunchKernelGGL(loss_kernel, dim3(NC * NBLK), dim3(128), 0, stream,
                       Wstg, Xstg, zf, kld, xsq, pmin, pidx);
    hipLaunchKernelGGL(reduce_kernel, dim3(NC), dim3(64), 0, stream, pmin, pidx, out, fidx);
    hipLaunchKernelGGL(final_kernel, dim3(NC * B), dim3(256), 0, stream, zf, dw, db, fidx, out);
}

// Round 11
// 357.394 us; speedup vs baseline: 3.4921x; 1.1824x over previous
//
#include <hip/hip_runtime.h>
#include <math.h>

#define B    64
#define D    3072
#define L    64
#define N    8000
#define NC   10
#define NT   160         // n per block (5 waves x 32)
#define WV   5           // waves per block
#define DC   32          // d per chunk
#define NBLKL (N / NT)   // 50
#define NCH  (D / DC)    // 96

#define LOGITS_OFF 0
#define RECS_OFF   640
#define MUS_OFF    (640 + NC * B * D)          // 1,966,720
#define LV_OFF     (MUS_OFF + NC * B * L)      // 2,007,680

// workspace byte offsets
#define WSTG_OFF 0                  // 960 regions x 9216B: [plane(4096)][lslot(512)][d(16)] + bias@8192
#define XSTG_OFF 8847360            // 96 regions x 8192B: [plane(4096)][dslot(1024)][b(16)]
#define KLD_OFF  9633792
#define XSQ_OFF  9665792
#define PMIN_OFF 9666048
#define PIDX_OFF 9986048

#define SCALE_UP   2048.0f
#define SCALE_DN   4.8828125e-4f    // 2^-11

typedef __attribute__((ext_vector_type(8)))  _Float16 h16x8;
typedef __attribute__((ext_vector_type(16))) float    f32x16;

typedef const __attribute__((address_space(1))) unsigned int* gas1_t;
typedef __attribute__((address_space(3))) unsigned int*       las3_t;

#define MFMA16(a, b, c) __builtin_amdgcn_mfma_f32_32x32x16_f16(a, b, c, 0, 0, 0)

__device__ __forceinline__ unsigned pack2h(_Float16 lo, _Float16 hi) {
    union { _Float16 h[2]; unsigned u; } x;
    x.h[0] = lo; x.h[1] = hi;
    return x.u;
}

// ---------------- prep: split W/X into slot-major fp16 planes, kld, x_sq ----------------
__global__ __launch_bounds__(256)
void prep_kernel(const float* __restrict__ xf, const float* __restrict__ zf,
                 const float* __restrict__ dw, const float* __restrict__ db,
                 unsigned short* __restrict__ Wstg, unsigned short* __restrict__ Xstg,
                 float* __restrict__ kld, float* __restrict__ xsq) {
    const int blk = blockIdx.x, t = threadIdx.x;
    if (blk < 960) {                       // W staging for (c, ch): transpose + split, slot-major
        const int c = blk / 96, ch = blk % 96;
        __shared__ float wt[32][68];
        #pragma unroll
        for (int k = 0; k < 8; ++k) {
            int l = (t >> 5) + 8 * k;      // 0..63
            int d = t & 31;
            wt[d][l] = dw[(size_t)(c * 64 + l) * D + ch * 32 + d];
        }
        __syncthreads();
        const int d = t >> 3, lg = t & 7, l0 = lg * 8;   // lg = l-slot
        float v[8];
        *(float4*)&v[0] = *(const float4*)&wt[d][l0];
        *(float4*)&v[4] = *(const float4*)&wt[d][l0 + 4];
        _Float16 p1[8], p2[8];
        #pragma unroll
        for (int j = 0; j < 8; ++j) {
            p1[j] = (_Float16)v[j];
            p2[j] = (_Float16)((v[j] - (float)p1[j]) * SCALE_UP);
        }
        unsigned short* reg = Wstg + (size_t)blk * 4608;   // 9216B region
        // slot-major: byte = plane*4096 + lg*512 + d*16  (16B-aligned, conflict-free reads)
        *(uint4*)&reg[lg * 256 + d * 8]        = *(const uint4*)&p1[0];
        *(uint4*)&reg[2048 + lg * 256 + d * 8] = *(const uint4*)&p2[0];
        if (t < 32) ((float*)(reg + 4096))[t] = db[(size_t)c * D + ch * 32 + t];
    } else if (blk < 1056) {               // X staging for ch: split, slot-major
        const int ch = blk - 960;
        const int b = t >> 2, dg = t & 3, dl0 = dg * 8;  // dg = d-slot
        float v[8];
        *(float4*)&v[0] = *(const float4*)&xf[(size_t)b * D + ch * 32 + dl0];
        *(float4*)&v[4] = *(const float4*)&xf[(size_t)b * D + ch * 32 + dl0 + 4];
        _Float16 p1[8], p2[8];
        #pragma unroll
        for (int j = 0; j < 8; ++j) {
            p1[j] = (_Float16)v[j];
            p2[j] = (_Float16)((v[j] - (float)p1[j]) * SCALE_UP);
        }
        unsigned short* reg = Xstg + (size_t)ch * 4096;    // 8192B region
        // slot-major: byte = plane*4096 + dg*1024 + b*16
        *(uint4*)&reg[dg * 512 + b * 8]        = *(const uint4*)&p1[0];
        *(uint4*)&reg[2048 + dg * 512 + b * 8] = *(const uint4*)&p2[0];
    } else if (blk < 1088) {               // kld[n] = 0.5*||z_n||^2
        int n = (blk - 1056) * 256 + t;
        if (n < N) {
            const float4* zp = (const float4*)(zf + (size_t)n * L);
            float s = 0.f;
            #pragma unroll
            for (int k = 0; k < 16; ++k) {
                float4 v4 = zp[k];
                s += v4.x * v4.x + v4.y * v4.y + v4.z * v4.z + v4.w * v4.w;
            }
            kld[n] = 0.5f * s;
        }
    } else {                               // xsq[b], blocks 1088..1151
        int b = blk - 1088;
        float s = 0.f;
        #pragma unroll
        for (int k = 0; k < 12; ++k) {
            float v = xf[(size_t)b * D + k * 256 + t];
            s = __builtin_fmaf(v, v, s);
        }
        for (int m = 1; m < 64; m <<= 1) s += __shfl_xor(s, m);
        __shared__ float ps[4];
        if ((t & 63) == 0) ps[t >> 6] = s;
        __syncthreads();
        if (t == 0) xsq[b] = ps[0] + ps[1] + ps[2] + ps[3];
    }
}

// ---------------- main: fp16 split MFMA fused loss (5 waves, NT=160) ----------------
__global__ __launch_bounds__(320, 2)
void loss_kernel(const unsigned short* __restrict__ Wstg, const unsigned short* __restrict__ Xstg,
                 const float* __restrict__ zf, const float* __restrict__ kld,
                 const float* __restrict__ xsq,
                 float* __restrict__ pmin, int* __restrict__ pidx) {
    const int tid  = threadIdx.x;
    const int wid  = tid >> 6;      // 0..4 : wave = 32-n group
    const int lane = tid & 63;
    const int lrow = lane & 31;
    const int h    = lane >> 5;

    // bijective XCD swizzle (nwg=500, 8 XCDs: q=62, r=4)
    int bid = blockIdx.x;
    {
        int xcd = bid & 7, idx = bid >> 3;
        bid = (xcd < 4 ? xcd * 63 : 252 + (xcd - 4) * 62) + idx;
    }
    const int c  = bid / NBLKL;
    const int nb = bid % NBLKL;
    const int n0 = nb * NT;

    __shared__ __align__(16) unsigned char stg[2][17408];  // [buf]: [0,9216)=W+bias, [9216,17408)=X
    __shared__ float  xsq_s[B];
    __shared__ double vmin_s[WV][B];
    __shared__ int    imin_s[WV][B];

    // ---- Z fragments: fp16 2-plane (plane1 scaled x2048) ----
    h16x8 zfrag[4][2];
    {
        const float* zr = zf + (size_t)(n0 + 32 * wid + lrow) * L;
        #pragma unroll
        for (int ks = 0; ks < 4; ++ks) {
            float4 za = *(const float4*)(zr + ks * 16 + h * 8);
            float4 zb = *(const float4*)(zr + ks * 16 + h * 8 + 4);
            float vv[8] = {za.x, za.y, za.z, za.w, zb.x, zb.y, zb.z, zb.w};
            #pragma unroll
            for (int e = 0; e < 8; ++e) {
                _Float16 a1 = (_Float16)vv[e];
                zfrag[ks][0][e] = a1;
                zfrag[ks][1][e] = (_Float16)((vv[e] - (float)a1) * SCALE_UP);
            }
        }
    }
    if (tid < B) xsq_s[tid] = xsq[tid];

    const char* wsrc = (const char*)(Wstg + (size_t)(c * 96) * 4608);
    const char* xsrc = (const char*)Xstg;

#define STAGE(buf_, ch_)  do {                                                          \
        if (wid == 0) {                                                                 \
            const char* g_ = wsrc + (size_t)(ch_) * 9216 + lane * 16;                   \
            char* l_ = (char*)&stg[buf_][0];                                            \
            _Pragma("unroll")                                                           \
            for (int i_ = 0; i_ < 9; ++i_)                                              \
                __builtin_amdgcn_global_load_lds((gas1_t)(g_ + i_ * 1024),              \
                                                 (las3_t)(l_ + i_ * 1024), 16, 0, 0);   \
        } else if (wid == 1) {                                                          \
            const char* g_ = xsrc + (size_t)(ch_) * 8192 + lane * 16;                   \
            char* l_ = (char*)&stg[buf_][9216];                                         \
            _Pragma("unroll")                                                           \
            for (int i_ = 0; i_ < 8; ++i_)                                              \
                __builtin_amdgcn_global_load_lds((gas1_t)(g_ + i_ * 1024),              \
                                                 (las3_t)(l_ + i_ * 1024), 16, 0, 0);   \
        } } while (0)

    // slot-major LDS byte offsets: addr = slot*stride + lane_row*16 (conflict-free)
    int woff[4];
    #pragma unroll
    for (int ks = 0; ks < 4; ++ks)
        woff[ks] = (2 * ks + h) * 512 + lrow * 16;
    int xoff[2][2];
    #pragma unroll
    for (int bh = 0; bh < 2; ++bh)
        #pragma unroll
        for (int ks2 = 0; ks2 < 2; ++ks2)
            xoff[bh][ks2] = (2 * ks2 + h) * 1024 + (32 * bh + lrow) * 16;

    f32x16 acc2a = (f32x16)0.0f, acc2b = (f32x16)0.0f;   // main plane cross
    f32x16 accca = (f32x16)0.0f, acccb = (f32x16)0.0f;   // correction via X plane2 (scaled x2048)
    f32x16 sh2a  = (f32x16)0.0f, sh2b  = (f32x16)0.0f;   // f32 shadow of main
    double racc_d = 0.0;

    STAGE(0, 0);
    __syncthreads();                     // drains vmcnt: buf0 staged

    int buf = 0;
    for (int ch = 0; ch < NCH; ++ch) {
        if (ch + 1 < NCH) STAGE(buf ^ 1, ch + 1);

        const unsigned char* base = &stg[buf][0];

        // ---- GEMM1: rt(main) = w1*z1 ; rtc(corr) = w1*z2' + w2'*z1 ----
        f32x16 rt  = (f32x16)0.0f;
        f32x16 rtc = (f32x16)0.0f;
        #pragma unroll
        for (int ks = 0; ks < 4; ++ks) {
            h16x8 w1 = *(const h16x8*)(base + woff[ks]);
            h16x8 w2 = *(const h16x8*)(base + 4096 + woff[ks]);
            rt  = MFMA16(w1, zfrag[ks][0], rt);
            rtc = MFMA16(w1, zfrag[ks][1], rtc);
            rtc = MFMA16(w2, zfrag[ks][0], rtc);
        }

        const float* biasb = (const float*)(base + 8192);
        float4 bq[4];
        #pragma unroll
        for (int q = 0; q < 4; ++q) bq[q] = *(const float4*)&biasb[8 * q + 4 * h];

        // ---- sigmoid + r^2 (raw v_rcp: 1-instr reciprocal, ~1ulp) ----
        float sv[16];
        float ch_r2 = 0.f;
        #pragma unroll
        for (int r_ = 0; r_ < 16; ++r_) {
            float a = __builtin_fmaf(rtc[r_], SCALE_DN, rt[r_]) + bq[r_ >> 2][r_ & 3];
            float r = __builtin_amdgcn_rcpf(1.0f + __expf(-a));
            sv[r_] = r;
            ch_r2 = __builtin_fmaf(r, r, ch_r2);
        }
        racc_d += (double)ch_r2;

        // ---- build GEMM2 B-fragments (single fp16 plane, permlane redistribution) ----
        h16x8 rfrag[2];
        #pragma unroll
        for (int ks2 = 0; ks2 < 2; ++ks2) {
            _Float16 p1[8];
            #pragma unroll
            for (int e = 0; e < 8; ++e)
                p1[e] = (_Float16)sv[8 * ks2 + e];
            unsigned A0 = pack2h(p1[0], p1[1]), A1 = pack2h(p1[2], p1[3]);
            unsigned B0 = pack2h(p1[4], p1[5]), B1 = pack2h(p1[6], p1[7]);
            auto r02 = __builtin_amdgcn_permlane32_swap((int)A0, (int)B0, false, false);
            auto r13 = __builtin_amdgcn_permlane32_swap((int)A1, (int)B1, false, false);
            union { unsigned u[4]; h16x8 v; } f;
            f.u[0] = (unsigned)r02[0]; f.u[1] = (unsigned)r13[0];
            f.u[2] = (unsigned)r02[1]; f.u[3] = (unsigned)r13[1];
            rfrag[ks2] = f.v;
        }

        // ---- GEMM2: main x1*r1 ; corr x2'*r1 (X plane2 carries the correction) ----
        const unsigned char* xb = base + 9216;
        #pragma unroll
        for (int ks2 = 0; ks2 < 2; ++ks2) {
            h16x8 x1a = *(const h16x8*)(xb + xoff[0][ks2]);
            h16x8 x1b = *(const h16x8*)(xb + xoff[1][ks2]);
            h16x8 x2a = *(const h16x8*)(xb + 4096 + xoff[0][ks2]);
            h16x8 x2b = *(const h16x8*)(xb + 4096 + xoff[1][ks2]);
            acc2a = MFMA16(x1a, rfrag[ks2], acc2a);
            acc2b = MFMA16(x1b, rfrag[ks2], acc2b);
            accca = MFMA16(x2a, rfrag[ks2], accca);
            acccb = MFMA16(x2b, rfrag[ks2], acccb);
        }

        if ((ch & 31) == 31) {           // shadow drain: bounds f32 acc rounding walk
            sh2a += acc2a; sh2b += acc2b;
            acc2a = (f32x16)0.0f; acc2b = (f32x16)0.0f;
        }

        __syncthreads();                 // drains prefetch vmcnt + protects buf reuse
        buf ^= 1;
    }
    sh2a += acc2a; sh2b += acc2b;

    // ---------------- epilogue: loss + argmin ----------------
    double racc_t = racc_d + __shfl_xor(racc_d, 32);
    const int nglob = n0 + 32 * wid + lrow;
    const double rk = racc_t + (double)kld[nglob];

    double lv[2][16];
    int    bi[2][16];
    #pragma unroll
    for (int bh = 0; bh < 2; ++bh)
        #pragma unroll
        for (int r_ = 0; r_ < 16; ++r_) {
            int bb = 32 * bh + (r_ & 3) + 8 * (r_ >> 2) + 4 * h;
            double cr = (bh == 0)
                ? ((double)sh2a[r_] + (double)accca[r_] * (double)SCALE_DN)
                : ((double)sh2b[r_] + (double)acccb[r_] * (double)SCALE_DN);
            lv[bh][r_] = (double)xsq_s[bb] + rk - 2.0 * cr;
            bi[bh][r_] = nglob;
        }
    #pragma unroll
    for (int m = 1; m <= 16; m <<= 1) {
        #pragma unroll
        for (int bh = 0; bh < 2; ++bh)
            #pragma unroll
            for (int r_ = 0; r_ < 16; ++r_) {
                double ov = __shfl_xor(lv[bh][r_], m);
                int    oi = __shfl_xor(bi[bh][r_], m);
                if (ov < lv[bh][r_] || (ov == lv[bh][r_] && oi < bi[bh][r_])) {
                    lv[bh][r_] = ov; bi[bh][r_] = oi;
                }
            }
    }
    if (lrow == 0) {
        #pragma unroll
        for (int bh = 0; bh < 2; ++bh)
            #pragma unroll
            for (int r_ = 0; r_ < 16; ++r_) {
                int bb = 32 * bh + (r_ & 3) + 8 * (r_ >> 2) + 4 * h;
                vmin_s[wid][bb] = lv[bh][r_];
                imin_s[wid][bb] = bi[bh][r_];
            }
    }
    __syncthreads();
    if (tid < B) {
        double bv = vmin_s[0][tid]; int bix = imin_s[0][tid];
        #pragma unroll
        for (int w = 1; w < WV; ++w) {
            double v = vmin_s[w][tid]; int i = imin_s[w][tid];
            if (v < bv || (v == bv && i < bix)) { bv = v; bix = i; }
        }
        pmin[((size_t)c * NBLKL + nb) * B + tid] = (float)bv;
        pidx[((size_t)c * NBLKL + nb) * B + tid] = bix;
    }
#undef STAGE
}

// ---------------- final: argmin reduce + selected reconstruction + mus + logvars ----------------
__global__ __launch_bounds__(256)
void final_kernel(const float* __restrict__ zf, const float* __restrict__ dw,
                  const float* __restrict__ db, const float* __restrict__ pmin,
                  const int* __restrict__ pidx, float* __restrict__ out) {
    const int c = blockIdx.x >> 6;
    const int b = blockIdx.x & 63;
    const int t = threadIdx.x;

    __shared__ float pv[64];
    __shared__ int   pi[64];
    __shared__ int   nsel_s;
    if (t < 64) {
        if (t < NBLKL) {
            pv[t] = pmin[((size_t)c * NBLKL + t) * B + b];
            pi[t] = pidx[((size_t)c * NBLKL + t) * B + b];
        } else { pv[t] = 3.4e38f; pi[t] = 0x7fffffff; }
    }
    __syncthreads();
    if (t < 64) {
        float v = pv[t]; int i = pi[t];
        for (int m = 1; m < 64; m <<= 1) {
            float ov = __shfl_xor(v, m);
            int   oi = __shfl_xor(i, m);
            if (ov < v || (ov == v && oi < i)) { v = ov; i = oi; }
        }
        if (t == 0) {
            out[LOGITS_OFF + b * NC + c] = -v;
            nsel_s = i;
        }
    }
    __syncthreads();
    const int n = nsel_s;
    __shared__ float zsh[64];
    if (t < 64) zsh[t] = zf[(size_t)n * L + t];
    __syncthreads();

    const float* wcc = dw + (size_t)c * L * D;
    float* rout = out + RECS_OFF + (size_t)(c * B + b) * D;
    #pragma unroll
    for (int k = 0; k < 3; ++k) {
        const int d0 = (t + k * 256) * 4;
        float4 a = *(const float4*)&db[(size_t)c * D + d0];
        #pragma unroll 16
        for (int l = 0; l < L; ++l) {
            const float zl = zsh[l];
            float4 w = *(const float4*)&wcc[(size_t)l * D + d0];
            a.x = __builtin_fmaf(zl, w.x, a.x);
            a.y = __builtin_fmaf(zl, w.y, a.y);
            a.z = __builtin_fmaf(zl, w.z, a.z);
            a.w = __builtin_fmaf(zl, w.w, a.w);
        }
        float4 r;
        r.x = 1.0f / (1.0f + __expf(-a.x));
        r.y = 1.0f / (1.0f + __expf(-a.y));
        r.z = 1.0f / (1.0f + __expf(-a.z));
        r.w = 1.0f / (1.0f + __expf(-a.w));
        *(float4*)&rout[d0] = r;
    }
    if (t < 64) {
        out[MUS_OFF + (size_t)(c * B + b) * L + t] = zsh[t];
        out[LV_OFF  + (size_t)(c * B + b) * L + t] = 0.0f;
    }
}

extern "C" void kernel_launch(void* const* d_in, const int* in_sizes, int n_in,
                              void* d_out, int out_size, void* d_ws, size_t ws_size,
                              hipStream_t stream) {
    const float* xf = (const float*)d_in[0];
    const float* zf = (const float*)d_in[1];
    const float* dw = (const float*)d_in[2];
    const float* db = (const float*)d_in[3];
    float* out = (float*)d_out;
    char* ws = (char*)d_ws;

    unsigned short* Wstg = (unsigned short*)(ws + WSTG_OFF);
    unsigned short* Xstg = (unsigned short*)(ws + XSTG_OFF);
    float* kld  = (float*)(ws + KLD_OFF);
    float* xsq  = (float*)(ws + XSQ_OFF);
    float* pmin = (float*)(ws + PMIN_OFF);
    int*   pidx = (int*)  (ws + PIDX_OFF);

    hipLaunchKernelGGL(prep_kernel, dim3(1152), dim3(256), 0, stream,
                       xf, zf, dw, db, Wstg, Xstg, kld, xsq);
    hipLaunchKernelGGL(loss_kernel, dim3(NC * NBLKL), dim3(320), 0, stream,
                       Wstg, Xstg, zf, kld, xsq, pmin, pidx);
    hipLaunchKernelGGL(final_kernel, dim3(NC * B), dim3(256), 0, stream,
                       zf, dw, db, pmin, pidx, out);
}